// Round 1
// baseline (383.151 us; speedup 1.0000x reference)
//
#include <hip/hip_runtime.h>
#include <math.h>

#define E   1024
#define H   16
#define DH  64
#define CD  512
#define S   2048
#define B   16
#define SRC (S + 1)      // 2049
#define SPAD 2052        // padded score row stride
#define SCALE 0.125f     // DH^-0.5

// ws layout (float offsets)
#define OFF_CTXP 0                 // [B][E]
#define OFF_Q0   16384             // [B][E]
#define OFF_BKP  32768             // [E]
#define OFF_Q1S  33792             // [B][E]  (scaled q after ctx proj)
#define OFF_CK   50176             // [B][E]
#define OFF_TT   66560             // t_T [f=1024][bh=256]
#define OFF_C0   328704            // [bh]
#define OFF_GP   328960            // g_part [4][bh][E]
#define OFF_SC   1377536           // scores [bh][SPAD]
#define OFF_WT   1902848           // w_T [b][s=0..2048][h]
#define OFF_UP   2427392           // u_part [16][b][h][E]
#define OFF_U    6621696           // u [b][h][E]
#define OFF_AP   6883840           // attn_pre [b][E]
// total 6900224 floats = 27.6 MB

// ---------------- stage 1: ctxp, q0, bkp ----------------
__global__ __launch_bounds__(256) void k_pre1(
    const float* __restrict__ query, const float* __restrict__ context,
    const float* __restrict__ ipw, const float* __restrict__ ipb,
    const float* __restrict__ cw, const float* __restrict__ cb,
    float* __restrict__ ws)
{
    int b = blockIdx.x >> 2;
    int e = ((blockIdx.x & 3) << 8) + threadIdx.x;
    const float* crow = cw + (size_t)e * (CD + E);
    const float* ctx  = context + b * CD;
    float acc = cb[e];
    for (int c = 0; c < CD; c += 4) {
        float4 w4 = *(const float4*)(crow + c);
        float4 x4 = *(const float4*)(ctx + c);
        acc += w4.x*x4.x + w4.y*x4.y + w4.z*x4.z + w4.w*x4.w;
    }
    ws[OFF_CTXP + b*E + e] = acc;

    const float* qrow = query + b * E;
    const float* wrow = ipw + (size_t)e * E;   // Wq row e
    float a2 = ipb[e];
    for (int f = 0; f < E; f += 4) {
        float4 w4 = *(const float4*)(wrow + f);
        float4 x4 = *(const float4*)(qrow + f);
        a2 += w4.x*x4.x + w4.y*x4.y + w4.z*x4.z + w4.w*x4.w;
    }
    ws[OFF_Q0 + b*E + e] = a2;

    if (b == 0) {   // bkp[e] = Wc2[e,:]·bk
        const float* c2 = crow + CD;
        const float* bk = ipb + E;
        float a3 = 0.f;
        for (int f = 0; f < E; f += 4) {
            float4 w4 = *(const float4*)(c2 + f);
            float4 x4 = *(const float4*)(bk + f);
            a3 += w4.x*x4.x + w4.y*x4.y + w4.z*x4.z + w4.w*x4.w;
        }
        ws[OFF_BKP + e] = a3;
    }
}

// ---------------- stage 2: q1s (scaled), ck ----------------
__global__ __launch_bounds__(256) void k_pre2(
    const float* __restrict__ cw, float* __restrict__ ws)
{
    int b = blockIdx.x >> 2;
    int e = ((blockIdx.x & 3) << 8) + threadIdx.x;
    const float* q0 = ws + OFF_Q0 + b*E;
    const float* c2row = cw + (size_t)e * (CD + E) + CD;  // Wc2 row e
    float acc = 0.f;
    for (int f = 0; f < E; f += 4) {
        float4 w4 = *(const float4*)(c2row + f);
        float4 x4 = *(const float4*)(q0 + f);
        acc += w4.x*x4.x + w4.y*x4.y + w4.z*x4.z + w4.w*x4.w;
    }
    float ctxp = ws[OFF_CTXP + b*E + e];
    ws[OFF_Q1S + b*E + e] = (ctxp + acc) * SCALE;
    ws[OFF_CK  + b*E + e] = ctxp + ws[OFF_BKP + e];
}

// ---------------- stage 3: t_T[f][bh] ----------------
__global__ __launch_bounds__(256) void k_pre3(
    const float* __restrict__ cw, float* __restrict__ ws)
{
    int bh = blockIdx.x >> 2;
    int f  = ((blockIdx.x & 3) << 8) + threadIdx.x;
    int b = bh >> 4, h = bh & 15;
    const float* q1 = ws + OFF_Q1S + b*E + h*DH;
    float acc = 0.f;
    #pragma unroll 8
    for (int d = 0; d < DH; ++d)
        acc += q1[d] * cw[(size_t)(h*DH + d)*(CD+E) + CD + f];
    ws[OFF_TT + f*256 + bh] = acc;
}

// ---------------- stage 3b: c0[bh], score at s=S ----------------
__global__ __launch_bounds__(256) void k_pre3b(
    const float* __restrict__ bias_k, float* __restrict__ ws)
{
    int bh = threadIdx.x;        // 1 block of 256
    int b = bh >> 4, h = bh & 15;
    const float* q1 = ws + OFF_Q1S + b*E + h*DH;
    const float* ck = ws + OFF_CK  + b*E + h*DH;
    const float* bk = bias_k + h*DH;
    float c0 = 0.f, sb = 0.f;
    for (int d = 0; d < DH; ++d) { float q = q1[d]; c0 += q*ck[d]; sb += q*bk[d]; }
    ws[OFF_C0 + bh] = c0;
    ws[OFF_SC + (size_t)bh*SPAD + S] = sb;   // bias_k position score
}

// ---------------- g_part[kc][bh][e] = partial over f-chunk ----------------
__global__ __launch_bounds__(256) void k_g(
    const float* __restrict__ ipw, float* __restrict__ ws)
{
    int kc = blockIdx.x >> 6;            // 0..3  (f chunk of 256)
    int nt = (blockIdx.x >> 4) & 3;      // n tile of 256
    int mt = blockIdx.x & 15;            // m tile of 16 (bh)
    int n  = (nt << 8) + threadIdx.x;
    int m0 = mt << 4;
    int f0 = kc << 8;
    const float* tT = ws + OFF_TT;
    const float* wk = ipw + (size_t)E * E;   // Wk rows
    float acc[16];
    #pragma unroll
    for (int m = 0; m < 16; ++m) acc[m] = 0.f;
    for (int f = f0; f < f0 + 256; ++f) {
        float wv = wk[(size_t)f*E + n];
        const float* tr = tT + f*256 + m0;   // uniform -> scalar loads
        #pragma unroll
        for (int m = 0; m < 16; ++m) acc[m] += tr[m] * wv;
    }
    float* gp = ws + OFF_GP + (size_t)kc * (256*E);
    #pragma unroll
    for (int m = 0; m < 16; ++m) gp[(size_t)(m0+m)*E + n] = acc[m];
}

// ---------------- scores[bh][s] = key·g + c0 ----------------
__global__ __launch_bounds__(1024) void k_scores(
    const float* __restrict__ key, float* __restrict__ ws)
{
    int b  = blockIdx.x >> 4;
    int s0 = (blockIdx.x & 15) << 7;     // 128 s per block
    int h  = threadIdx.x >> 6;
    int l  = threadIdx.x & 63;
    int bh = b*16 + h;
    // lane l holds g elements e = j*256 + l*4 + i (sum 4 k-partials)
    float4 g[4];
    #pragma unroll
    for (int j = 0; j < 4; ++j) {
        int e = j*256 + l*4;
        const float* gp = ws + OFF_GP + (size_t)bh*E + e;
        float4 gv = *(const float4*)gp;
        #pragma unroll
        for (int c = 1; c < 4; ++c) {
            float4 t = *(const float4*)(gp + (size_t)c*(256*E));
            gv.x += t.x; gv.y += t.y; gv.z += t.z; gv.w += t.w;
        }
        g[j] = gv;
    }
    float c0 = ws[OFF_C0 + bh];
    float* srow = ws + OFF_SC + (size_t)bh*SPAD;
    for (int i = 0; i < 128; ++i) {
        int s = s0 + i;
        const float* kr = key + ((size_t)(s*B + b) << 10);
        float acc = 0.f;
        #pragma unroll
        for (int j = 0; j < 4; ++j) {
            float4 kv = *(const float4*)(kr + j*256 + l*4);
            acc += kv.x*g[j].x + kv.y*g[j].y + kv.z*g[j].z + kv.w*g[j].w;
        }
        #pragma unroll
        for (int m = 1; m < 64; m <<= 1) acc += __shfl_xor(acc, m, 64);
        if (l == 0) srow[s] = acc + c0;
    }
}

// ---------------- softmax per (b,h) row; write w_T[b][s][h] ----------------
__global__ __launch_bounds__(256) void k_softmax(float* __restrict__ ws)
{
    int bh = blockIdx.x; int b = bh >> 4, h = bh & 15;
    int tid = threadIdx.x, lane = tid & 63, wid = tid >> 6;
    const float* row = ws + OFF_SC + (size_t)bh*SPAD;
    __shared__ float red[4];
    float v[9];
    float m = -1e30f;
    #pragma unroll
    for (int i = 0; i < 9; ++i) {
        int s = tid + (i << 8);
        if (s < SRC) { v[i] = row[s]; m = fmaxf(m, v[i]); } else v[i] = -1e30f;
    }
    #pragma unroll
    for (int k = 1; k < 64; k <<= 1) m = fmaxf(m, __shfl_xor(m, k, 64));
    if (lane == 0) red[wid] = m;
    __syncthreads();
    m = fmaxf(fmaxf(red[0], red[1]), fmaxf(red[2], red[3]));
    __syncthreads();
    float sum = 0.f;
    #pragma unroll
    for (int i = 0; i < 9; ++i) {
        int s = tid + (i << 8);
        if (s < SRC) { v[i] = expf(v[i] - m); sum += v[i]; }
    }
    #pragma unroll
    for (int k = 1; k < 64; k <<= 1) sum += __shfl_xor(sum, k, 64);
    if (lane == 0) red[wid] = sum;
    __syncthreads();
    sum = red[0] + red[1] + red[2] + red[3];
    float inv = 1.0f / sum;
    float* wt = ws + OFF_WT;
    #pragma unroll
    for (int i = 0; i < 9; ++i) {
        int s = tid + (i << 8);
        if (s < SRC) wt[((size_t)(b*SRC + s) << 4) + h] = v[i] * inv;
    }
}

// ---------------- avg_weights output ----------------
__global__ __launch_bounds__(256) void k_avg(
    const float* __restrict__ ws, float* __restrict__ out)
{
    int id = blockIdx.x * 256 + threadIdx.x;
    if (id >= B * SRC) return;
    const float* p = ws + OFF_WT + (size_t)id * 16;
    float a = 0.f;
    #pragma unroll
    for (int j = 0; j < 16; j += 4) {
        float4 w4 = *(const float4*)(p + j);
        a += w4.x + w4.y + w4.z + w4.w;
    }
    out[B*E + id] = a * (1.0f / H);
}

// ---------------- u_part[sc][b][h][f] = Σ_s w·value ----------------
__global__ __launch_bounds__(256) void k_u(
    const float* __restrict__ value, float* __restrict__ ws)
{
    int b  = blockIdx.x >> 5;
    int sc = (blockIdx.x >> 1) & 15;     // 16 s-chunks of 128
    int fh = blockIdx.x & 1;             // f half
    int f  = (fh << 9) + threadIdx.x * 2;
    float2 acc[16];
    #pragma unroll
    for (int h = 0; h < 16; ++h) { acc[h].x = 0.f; acc[h].y = 0.f; }
    int s0 = sc << 7;
    for (int i = 0; i < 128; ++i) {
        int s = s0 + i;
        const float* wr = ws + OFF_WT + ((size_t)(b*SRC + s) << 4); // uniform
        float2 vv = *(const float2*)(value + ((size_t)(s*B + b) << 10) + f);
        #pragma unroll
        for (int h = 0; h < 16; ++h) {
            float wv = wr[h];
            acc[h].x += wv * vv.x; acc[h].y += wv * vv.y;
        }
    }
    float* up = ws + OFF_UP + ((size_t)(sc*B + b) << 4) * E;
    #pragma unroll
    for (int h = 0; h < 16; ++h)
        *(float2*)(up + (size_t)h*E + f) = acc[h];
}

// ---------------- reduce u_part ----------------
__global__ __launch_bounds__(256) void k_ured(float* __restrict__ ws)
{
    int id = blockIdx.x * 256 + threadIdx.x;   // 262144 threads
    float a = 0.f;
    #pragma unroll
    for (int c = 0; c < 16; ++c) a += ws[OFF_UP + (size_t)c*(B*H*E) + id];
    ws[OFF_U + id] = a;
}

// ---------------- attn_pre[b][e] ----------------
__global__ __launch_bounds__(256) void k_attnpre(
    const float* __restrict__ ipw, const float* __restrict__ ipb,
    const float* __restrict__ bias_v, float* __restrict__ ws)
{
    int b = blockIdx.x >> 2;
    int e = ((blockIdx.x & 3) << 8) + threadIdx.x;
    int h = e >> 6;
    const float* wvr = ipw + (size_t)(2*E + e) * E;   // Wv row e
    const float* ur  = ws + OFF_U + (size_t)(b*16 + h) * E;
    float acc = 0.f;
    for (int ff = 0; ff < E; ff += 4) {
        float4 w4 = *(const float4*)(wvr + ff);
        float4 u4 = *(const float4*)(ur + ff);
        acc += w4.x*u4.x + w4.y*u4.y + w4.z*u4.z + w4.w*u4.w;
    }
    float wS = ws[OFF_WT + ((size_t)(b*SRC + S) << 4) + h];
    acc += ipb[2*E + e] * (1.0f - wS) + wS * bias_v[e];
    ws[OFF_AP + b*E + e] = acc;
}

// ---------------- out projection ----------------
__global__ __launch_bounds__(256) void k_out(
    const float* __restrict__ ow, const float* __restrict__ ob,
    const float* __restrict__ ws, float* __restrict__ out)
{
    int b = blockIdx.x >> 2;
    int o = ((blockIdx.x & 3) << 8) + threadIdx.x;
    const float* wr = ow + (size_t)o * E;
    const float* ap = ws + OFF_AP + b*E;
    float acc = ob[o];
    for (int e = 0; e < E; e += 4) {
        float4 w4 = *(const float4*)(wr + e);
        float4 a4 = *(const float4*)(ap + e);
        acc += w4.x*a4.x + w4.y*a4.y + w4.z*a4.z + w4.w*a4.w;
    }
    out[b*E + o] = acc;
}

extern "C" void kernel_launch(void* const* d_in, const int* in_sizes, int n_in,
                              void* d_out, int out_size, void* d_ws, size_t ws_size,
                              hipStream_t stream)
{
    const float* query   = (const float*)d_in[0];
    const float* key     = (const float*)d_in[1];
    const float* value   = (const float*)d_in[2];
    const float* context = (const float*)d_in[3];
    const float* ipw     = (const float*)d_in[4];
    const float* ipb     = (const float*)d_in[5];
    const float* cw      = (const float*)d_in[6];
    const float* cb      = (const float*)d_in[7];
    const float* ow      = (const float*)d_in[8];
    const float* ob      = (const float*)d_in[9];
    const float* bias_k  = (const float*)d_in[10];
    const float* bias_v  = (const float*)d_in[11];
    float* out = (float*)d_out;
    float* ws  = (float*)d_ws;

    hipLaunchKernelGGL(k_pre1,    dim3(64),   dim3(256),  0, stream, query, context, ipw, ipb, cw, cb, ws);
    hipLaunchKernelGGL(k_pre2,    dim3(64),   dim3(256),  0, stream, cw, ws);
    hipLaunchKernelGGL(k_pre3,    dim3(1024), dim3(256),  0, stream, cw, ws);
    hipLaunchKernelGGL(k_pre3b,   dim3(1),    dim3(256),  0, stream, bias_k, ws);
    hipLaunchKernelGGL(k_g,       dim3(256),  dim3(256),  0, stream, ipw, ws);
    hipLaunchKernelGGL(k_scores,  dim3(256),  dim3(1024), 0, stream, key, ws);
    hipLaunchKernelGGL(k_softmax, dim3(256),  dim3(256),  0, stream, ws);
    hipLaunchKernelGGL(k_avg,     dim3(129),  dim3(256),  0, stream, ws, out);
    hipLaunchKernelGGL(k_u,       dim3(512),  dim3(256),  0, stream, value, ws);
    hipLaunchKernelGGL(k_ured,    dim3(1024), dim3(256),  0, stream, ws);
    hipLaunchKernelGGL(k_attnpre, dim3(64),   dim3(256),  0, stream, ipw, ipb, bias_v, ws);
    hipLaunchKernelGGL(k_out,     dim3(64),   dim3(256),  0, stream, ow, ob, ws, out);
}

// Round 2
// 285.031 us; speedup vs baseline: 1.3442x; 1.3442x over previous
//
#include <hip/hip_runtime.h>
#include <math.h>

#define E   1024
#define H   16
#define DH  64
#define CD  512
#define S   2048
#define B   16
#define SRC (S + 1)      // 2049
#define SPAD 2052        // padded score row stride
#define SCALE 0.125f     // DH^-0.5

// ws layout (float offsets) — unchanged from R1; final g overwrites GP slab 0
#define OFF_CTXP 0                 // [B][E]
#define OFF_Q0   16384             // [B][E]
#define OFF_BKP  32768             // [E]
#define OFF_Q1S  33792             // [B][E]  (scaled q after ctx proj)
#define OFF_CK   50176             // [B][E]
#define OFF_TT   66560             // t_T [f=1024][bh=256]
#define OFF_C0   328704            // [bh]
#define OFF_GP   328960            // g_part [4][bh][E]; after k_gsum, [0] holds final g
#define OFF_SC   1377536           // scores [bh][SPAD]
#define OFF_WT   1902848           // w_T [b][s=0..2048][h]
#define OFF_UP   2427392           // u_part [16][b][h][E]
#define OFF_U    6621696           // u [b][h][E]
#define OFF_AP   6883840           // attn_pre [b][E]

// ---------------- stage 1: ctxp, q0, bkp (16-lane-group GEMV) ----------------
__global__ __launch_bounds__(256) void k_pre1(
    const float* __restrict__ query, const float* __restrict__ context,
    const float* __restrict__ ipw, const float* __restrict__ ipb,
    const float* __restrict__ cw, const float* __restrict__ cb,
    float* __restrict__ ws)
{
    int b  = blockIdx.x >> 6;
    int et = blockIdx.x & 63;
    int grp = threadIdx.x >> 4, l = threadIdx.x & 15;
    int e = et * 16 + grp;
    const float* crow = cw + (size_t)e * (CD + E);
    const float* ctx  = context + b * CD;
    float a1 = 0.f;
    #pragma unroll
    for (int c = l * 4; c < CD; c += 64) {
        float4 w4 = *(const float4*)(crow + c);
        float4 x4 = *(const float4*)(ctx + c);
        a1 += w4.x*x4.x + w4.y*x4.y + w4.z*x4.z + w4.w*x4.w;
    }
    const float* qrow = query + b * E;
    const float* wrow = ipw + (size_t)e * E;   // Wq row e
    float a2 = 0.f;
    #pragma unroll
    for (int f = l * 4; f < E; f += 64) {
        float4 w4 = *(const float4*)(wrow + f);
        float4 x4 = *(const float4*)(qrow + f);
        a2 += w4.x*x4.x + w4.y*x4.y + w4.z*x4.z + w4.w*x4.w;
    }
    float a3 = 0.f;
    if (b == 0) {   // bkp[e] = Wc2[e,:]·bias_k_pre (= ipb[E:2E])
        const float* c2 = crow + CD;
        const float* bk = ipb + E;
        #pragma unroll
        for (int f = l * 4; f < E; f += 64) {
            float4 w4 = *(const float4*)(c2 + f);
            float4 x4 = *(const float4*)(bk + f);
            a3 += w4.x*x4.x + w4.y*x4.y + w4.z*x4.z + w4.w*x4.w;
        }
    }
    #pragma unroll
    for (int m = 8; m >= 1; m >>= 1) {
        a1 += __shfl_xor(a1, m, 64);
        a2 += __shfl_xor(a2, m, 64);
        a3 += __shfl_xor(a3, m, 64);
    }
    if (l == 0) {
        ws[OFF_CTXP + b*E + e] = a1 + cb[e];
        ws[OFF_Q0   + b*E + e] = a2 + ipb[e];
        if (b == 0) ws[OFF_BKP + e] = a3;
    }
}

// ---------------- stage 2: q1s (scaled), ck ----------------
__global__ __launch_bounds__(256) void k_pre2(
    const float* __restrict__ cw, float* __restrict__ ws)
{
    int b  = blockIdx.x >> 6;
    int et = blockIdx.x & 63;
    int grp = threadIdx.x >> 4, l = threadIdx.x & 15;
    int e = et * 16 + grp;
    const float* q0 = ws + OFF_Q0 + b*E;
    const float* c2row = cw + (size_t)e * (CD + E) + CD;  // Wc2 row e
    float acc = 0.f;
    #pragma unroll
    for (int f = l * 4; f < E; f += 64) {
        float4 w4 = *(const float4*)(c2row + f);
        float4 x4 = *(const float4*)(q0 + f);
        acc += w4.x*x4.x + w4.y*x4.y + w4.z*x4.z + w4.w*x4.w;
    }
    #pragma unroll
    for (int m = 8; m >= 1; m >>= 1) acc += __shfl_xor(acc, m, 64);
    if (l == 0) {
        float ctxp = ws[OFF_CTXP + b*E + e];
        ws[OFF_Q1S + b*E + e] = (ctxp + acc) * SCALE;
        ws[OFF_CK  + b*E + e] = ctxp + ws[OFF_BKP + e];
    }
}

// ---------------- stage 3: t_T[f][bh] ----------------
__global__ __launch_bounds__(256) void k_pre3(
    const float* __restrict__ cw, float* __restrict__ ws)
{
    int bh = blockIdx.x >> 2;
    int f  = ((blockIdx.x & 3) << 8) + threadIdx.x;
    int b = bh >> 4, h = bh & 15;
    const float* q1 = ws + OFF_Q1S + b*E + h*DH;
    float acc = 0.f;
    #pragma unroll 8
    for (int d = 0; d < DH; ++d)
        acc += q1[d] * cw[(size_t)(h*DH + d)*(CD+E) + CD + f];
    ws[OFF_TT + f*256 + bh] = acc;
}

// ---------------- stage 3b: c0[bh], score at s=S ----------------
__global__ __launch_bounds__(256) void k_pre3b(
    const float* __restrict__ bias_k, float* __restrict__ ws)
{
    int bh = threadIdx.x;        // 1 block of 256
    int b = bh >> 4, h = bh & 15;
    const float* q1 = ws + OFF_Q1S + b*E + h*DH;
    const float* ck = ws + OFF_CK  + b*E + h*DH;
    const float* bk = bias_k + h*DH;
    float c0 = 0.f, sb = 0.f;
    for (int d = 0; d < DH; ++d) { float q = q1[d]; c0 += q*ck[d]; sb += q*bk[d]; }
    ws[OFF_C0 + bh] = c0;
    ws[OFF_SC + (size_t)bh*SPAD + S] = sb;   // bias_k position score
}

// ---------------- g_part[kc][bh][e] ----------------
__global__ __launch_bounds__(256) void k_g(
    const float* __restrict__ ipw, float* __restrict__ ws)
{
    int kc = blockIdx.x >> 6;            // 0..3  (f chunk of 256)
    int nt = (blockIdx.x >> 4) & 3;      // n tile of 256
    int mt = blockIdx.x & 15;            // m tile of 16 (bh)
    int n  = (nt << 8) + threadIdx.x;
    int m0 = mt << 4;
    int f0 = kc << 8;
    const float* tT = ws + OFF_TT;
    const float* wk = ipw + (size_t)E * E;   // Wk rows
    float acc[16];
    #pragma unroll
    for (int m = 0; m < 16; ++m) acc[m] = 0.f;
    for (int f = f0; f < f0 + 256; ++f) {
        float wv = wk[(size_t)f*E + n];
        const float* tr = tT + f*256 + m0;   // uniform -> scalar loads
        #pragma unroll
        for (int m = 0; m < 16; ++m) acc[m] += tr[m] * wv;
    }
    float* gp = ws + OFF_GP + (size_t)kc * (256*E);
    #pragma unroll
    for (int m = 0; m < 16; ++m) gp[(size_t)(m0+m)*E + n] = acc[m];
}

// ---------------- sum 4 g partials into slab 0 ----------------
__global__ __launch_bounds__(256) void k_gsum(float* __restrict__ ws)
{
    int id = blockIdx.x * 256 + threadIdx.x;   // 262144 threads
    float a = ws[OFF_GP + id]
            + ws[OFF_GP + 1*(256*E) + id]
            + ws[OFF_GP + 2*(256*E) + id]
            + ws[OFF_GP + 3*(256*E) + id];
    ws[OFF_GP + id] = a;
}

// ---------------- scores[bh][s] = key·g + c0 (broadcast-wave layout) -------
// thread = (h = tid&15, s-slot = tid>>4); 16 h-lanes issue identical key
// addresses (merged); each thread owns 2 full dots -> no cross-lane reduce.
__global__ __launch_bounds__(256) void k_scores(
    const float* __restrict__ key, float* __restrict__ ws)
{
    __shared__ float4 g4[4096];   // [c=256][h=16]  h-minor: bank start = 4h
    int b  = blockIdx.x >> 5;
    int sc = blockIdx.x & 31;     // 32 chunks of 64 s
    const float* gsrc = ws + OFF_GP + (size_t)(b*16)*E;   // final g
    for (int i = threadIdx.x; i < 4096; i += 256) {
        int h = i & 15, c = i >> 4;
        g4[c*16 + h] = *(const float4*)(gsrc + (size_t)h*E + c*4);
    }
    __syncthreads();
    int h  = threadIdx.x & 15;
    int sl = threadIdx.x >> 4;    // 0..15
    int bh = b*16 + h;
    float c0 = ws[OFF_C0 + bh];
    float* srow = ws + OFF_SC + (size_t)bh*SPAD;
    #pragma unroll
    for (int pass = 0; pass < 2; ++pass) {
        int s0 = sc*64 + pass*32 + sl;
        const float* kr0 = key + (((size_t)s0*B + b) << 10);
        const float* kr1 = kr0 + ((size_t)(16*B) << 10);   // row s0+16
        float a00=0.f,a01=0.f,a02=0.f,a03=0.f;
        float a10=0.f,a11=0.f,a12=0.f,a13=0.f;
        for (int e = 0; e < 1024; e += 16) {
            int c = (e >> 2) * 16 + h;
            float4 g0 = g4[c];
            float4 g1 = g4[c + 16];
            float4 g2 = g4[c + 32];
            float4 g3 = g4[c + 48];
            float4 p0 = *(const float4*)(kr0 + e);
            float4 p1 = *(const float4*)(kr0 + e + 4);
            float4 p2 = *(const float4*)(kr0 + e + 8);
            float4 p3 = *(const float4*)(kr0 + e + 12);
            float4 q0 = *(const float4*)(kr1 + e);
            float4 q1 = *(const float4*)(kr1 + e + 4);
            float4 q2 = *(const float4*)(kr1 + e + 8);
            float4 q3 = *(const float4*)(kr1 + e + 12);
            a00 += p0.x*g0.x + p0.y*g0.y + p0.z*g0.z + p0.w*g0.w;
            a01 += p1.x*g1.x + p1.y*g1.y + p1.z*g1.z + p1.w*g1.w;
            a02 += p2.x*g2.x + p2.y*g2.y + p2.z*g2.z + p2.w*g2.w;
            a03 += p3.x*g3.x + p3.y*g3.y + p3.z*g3.z + p3.w*g3.w;
            a10 += q0.x*g0.x + q0.y*g0.y + q0.z*g0.z + q0.w*g0.w;
            a11 += q1.x*g1.x + q1.y*g1.y + q1.z*g1.z + q1.w*g1.w;
            a12 += q2.x*g2.x + q2.y*g2.y + q2.z*g2.z + q2.w*g2.w;
            a13 += q3.x*g3.x + q3.y*g3.y + q3.z*g3.z + q3.w*g3.w;
        }
        srow[s0]      = a00+a01+a02+a03 + c0;
        srow[s0 + 16] = a10+a11+a12+a13 + c0;
    }
}

// ---------------- softmax per (b,h) row; write w_T[b][s][h] ----------------
__global__ __launch_bounds__(256) void k_softmax(float* __restrict__ ws)
{
    int bh = blockIdx.x; int b = bh >> 4, h = bh & 15;
    int tid = threadIdx.x, lane = tid & 63, wid = tid >> 6;
    const float* row = ws + OFF_SC + (size_t)bh*SPAD;
    __shared__ float red[4];
    float v[9];
    float m = -1e30f;
    #pragma unroll
    for (int i = 0; i < 9; ++i) {
        int s = tid + (i << 8);
        if (s < SRC) { v[i] = row[s]; m = fmaxf(m, v[i]); } else v[i] = -1e30f;
    }
    #pragma unroll
    for (int k = 1; k < 64; k <<= 1) m = fmaxf(m, __shfl_xor(m, k, 64));
    if (lane == 0) red[wid] = m;
    __syncthreads();
    m = fmaxf(fmaxf(red[0], red[1]), fmaxf(red[2], red[3]));
    __syncthreads();
    float sum = 0.f;
    #pragma unroll
    for (int i = 0; i < 9; ++i) {
        int s = tid + (i << 8);
        if (s < SRC) { v[i] = expf(v[i] - m); sum += v[i]; }
    }
    #pragma unroll
    for (int k = 1; k < 64; k <<= 1) sum += __shfl_xor(sum, k, 64);
    if (lane == 0) red[wid] = sum;
    __syncthreads();
    sum = red[0] + red[1] + red[2] + red[3];
    float inv = 1.0f / sum;
    float* wt = ws + OFF_WT;
    #pragma unroll
    for (int i = 0; i < 9; ++i) {
        int s = tid + (i << 8);
        if (s < SRC) wt[((size_t)(b*SRC + s) << 4) + h] = v[i] * inv;
    }
}

// ---------------- avg_weights output ----------------
__global__ __launch_bounds__(256) void k_avg(
    const float* __restrict__ ws, float* __restrict__ out)
{
    int id = blockIdx.x * 256 + threadIdx.x;
    if (id >= B * SRC) return;
    const float* p = ws + OFF_WT + (size_t)id * 16;
    float a = 0.f;
    #pragma unroll
    for (int j = 0; j < 16; j += 4) {
        float4 w4 = *(const float4*)(p + j);
        a += w4.x + w4.y + w4.z + w4.w;
    }
    out[B*E + id] = a * (1.0f / H);
}

// ---------------- u_part[sc][b][h][f] = Σ_s w·value ----------------
__global__ __launch_bounds__(256) void k_u(
    const float* __restrict__ value, float* __restrict__ ws)
{
    int b  = blockIdx.x >> 5;
    int sc = (blockIdx.x >> 1) & 15;     // 16 s-chunks of 128
    int fh = blockIdx.x & 1;             // f half
    int f  = (fh << 9) + threadIdx.x * 2;
    float2 acc[16];
    #pragma unroll
    for (int h = 0; h < 16; ++h) { acc[h].x = 0.f; acc[h].y = 0.f; }
    int s0 = sc << 7;
    for (int i = 0; i < 128; ++i) {
        int s = s0 + i;
        const float* wr = ws + OFF_WT + ((size_t)(b*SRC + s) << 4); // uniform
        float2 vv = *(const float2*)(value + (((size_t)s*B + b) << 10) + f);
        #pragma unroll
        for (int h = 0; h < 16; ++h) {
            float wv = wr[h];
            acc[h].x += wv * vv.x; acc[h].y += wv * vv.y;
        }
    }
    float* up = ws + OFF_UP + ((size_t)(sc*B + b) << 4) * E;
    #pragma unroll
    for (int h = 0; h < 16; ++h)
        *(float2*)(up + (size_t)h*E + f) = acc[h];
}

// ---------------- reduce u_part ----------------
__global__ __launch_bounds__(256) void k_ured(float* __restrict__ ws)
{
    int id = blockIdx.x * 256 + threadIdx.x;   // 262144 threads
    float a = 0.f;
    #pragma unroll
    for (int c = 0; c < 16; ++c) a += ws[OFF_UP + (size_t)c*(B*H*E) + id];
    ws[OFF_U + id] = a;
}

// ---------------- attn_pre[b][e] (16-lane-group GEMV) ----------------
__global__ __launch_bounds__(256) void k_attnpre(
    const float* __restrict__ ipw, const float* __restrict__ ipb,
    const float* __restrict__ bias_v, float* __restrict__ ws)
{
    int b  = blockIdx.x >> 6;
    int et = blockIdx.x & 63;
    int grp = threadIdx.x >> 4, l = threadIdx.x & 15;
    int e = et * 16 + grp;
    int h = e >> 6;
    const float* wvr = ipw + (size_t)(2*E + e) * E;   // Wv row e
    const float* ur  = ws + OFF_U + (size_t)(b*16 + h) * E;
    float acc = 0.f;
    #pragma unroll
    for (int ff = l * 4; ff < E; ff += 64) {
        float4 w4 = *(const float4*)(wvr + ff);
        float4 u4 = *(const float4*)(ur + ff);
        acc += w4.x*u4.x + w4.y*u4.y + w4.z*u4.z + w4.w*u4.w;
    }
    #pragma unroll
    for (int m = 8; m >= 1; m >>= 1) acc += __shfl_xor(acc, m, 64);
    if (l == 0) {
        float wS = ws[OFF_WT + ((size_t)(b*SRC + S) << 4) + h];
        ws[OFF_AP + b*E + e] = acc + ipb[2*E + e] * (1.0f - wS) + wS * bias_v[e];
    }
}

// ---------------- out projection (16-lane-group GEMV) ----------------
__global__ __launch_bounds__(256) void k_out(
    const float* __restrict__ ow, const float* __restrict__ ob,
    const float* __restrict__ ws, float* __restrict__ out)
{
    int b  = blockIdx.x >> 6;
    int et = blockIdx.x & 63;
    int grp = threadIdx.x >> 4, l = threadIdx.x & 15;
    int o = et * 16 + grp;
    const float* wr = ow + (size_t)o * E;
    const float* ap = ws + OFF_AP + b*E;
    float acc = 0.f;
    #pragma unroll
    for (int e = l * 4; e < E; e += 64) {
        float4 w4 = *(const float4*)(wr + e);
        float4 a4 = *(const float4*)(ap + e);
        acc += w4.x*a4.x + w4.y*a4.y + w4.z*a4.z + w4.w*a4.w;
    }
    #pragma unroll
    for (int m = 8; m >= 1; m >>= 1) acc += __shfl_xor(acc, m, 64);
    if (l == 0) out[b*E + o] = acc + ob[o];
}

extern "C" void kernel_launch(void* const* d_in, const int* in_sizes, int n_in,
                              void* d_out, int out_size, void* d_ws, size_t ws_size,
                              hipStream_t stream)
{
    const float* query   = (const float*)d_in[0];
    const float* key     = (const float*)d_in[1];
    const float* value   = (const float*)d_in[2];
    const float* context = (const float*)d_in[3];
    const float* ipw     = (const float*)d_in[4];
    const float* ipb     = (const float*)d_in[5];
    const float* cw      = (const float*)d_in[6];
    const float* cb      = (const float*)d_in[7];
    const float* ow      = (const float*)d_in[8];
    const float* ob      = (const float*)d_in[9];
    const float* bias_k  = (const float*)d_in[10];
    const float* bias_v  = (const float*)d_in[11];
    float* out = (float*)d_out;
    float* ws  = (float*)d_ws;

    hipLaunchKernelGGL(k_pre1,    dim3(1024), dim3(256),  0, stream, query, context, ipw, ipb, cw, cb, ws);
    hipLaunchKernelGGL(k_pre2,    dim3(1024), dim3(256),  0, stream, cw, ws);
    hipLaunchKernelGGL(k_pre3,    dim3(1024), dim3(256),  0, stream, cw, ws);
    hipLaunchKernelGGL(k_pre3b,   dim3(1),    dim3(256),  0, stream, bias_k, ws);
    hipLaunchKernelGGL(k_g,       dim3(256),  dim3(256),  0, stream, ipw, ws);
    hipLaunchKernelGGL(k_gsum,    dim3(1024), dim3(256),  0, stream, ws);
    hipLaunchKernelGGL(k_scores,  dim3(512),  dim3(256),  0, stream, key, ws);
    hipLaunchKernelGGL(k_softmax, dim3(256),  dim3(256),  0, stream, ws);
    hipLaunchKernelGGL(k_avg,     dim3(129),  dim3(256),  0, stream, ws, out);
    hipLaunchKernelGGL(k_u,       dim3(512),  dim3(256),  0, stream, value, ws);
    hipLaunchKernelGGL(k_ured,    dim3(1024), dim3(256),  0, stream, ws);
    hipLaunchKernelGGL(k_attnpre, dim3(1024), dim3(256),  0, stream, ipw, ipb, bias_v, ws);
    hipLaunchKernelGGL(k_out,     dim3(1024), dim3(256),  0, stream, ow, ob, ws, out);
}

// Round 3
// 208.924 us; speedup vs baseline: 1.8339x; 1.3643x over previous
//
#include <hip/hip_runtime.h>
#include <math.h>

#define E   1024
#define H   16
#define DH  64
#define CD  512
#define S   2048
#define B   16
#define SRC (S + 1)      // 2049
#define SPAD 2052        // padded score row stride
#define SCALE 0.125f     // DH^-0.5

// ws layout (float offsets)
#define OFF_CTXP 0                 // [B][E]
#define OFF_Q0   16384             // [B][E]
#define OFF_BKP  32768             // [E]
#define OFF_Q1S  33792             // [B][E]  (scaled q after ctx proj)
#define OFF_CK   50176             // [B][E]
#define OFF_TT   66560             // t_T [f=1024][bh=256]
#define OFF_C0   328704            // [bh]
#define OFF_GP   328960            // g_part [4][bh][E]; after k_gsum, [0] holds final g
#define OFF_SC   1377536           // scores [bh][SPAD]
#define OFF_WT   1902848           // w_T [b][s=0..2048][h]
#define OFF_UP   2427392           // u_part [16][b][h][E]
#define OFF_U    6621696           // u [b][h][E]
#define OFF_AP   6883840           // attn_pre [b][E]

// ---------------- stage 1: ctxp, q0, bkp (16-lane-group GEMV) ----------------
__global__ __launch_bounds__(256) void k_pre1(
    const float* __restrict__ query, const float* __restrict__ context,
    const float* __restrict__ ipw, const float* __restrict__ ipb,
    const float* __restrict__ cw, const float* __restrict__ cb,
    float* __restrict__ ws)
{
    int b  = blockIdx.x >> 6;
    int et = blockIdx.x & 63;
    int grp = threadIdx.x >> 4, l = threadIdx.x & 15;
    int e = et * 16 + grp;
    const float* crow = cw + (size_t)e * (CD + E);
    const float* ctx  = context + b * CD;
    float a1 = 0.f;
    #pragma unroll
    for (int c = l * 4; c < CD; c += 64) {
        float4 w4 = *(const float4*)(crow + c);
        float4 x4 = *(const float4*)(ctx + c);
        a1 += w4.x*x4.x + w4.y*x4.y + w4.z*x4.z + w4.w*x4.w;
    }
    const float* qrow = query + b * E;
    const float* wrow = ipw + (size_t)e * E;   // Wq row e
    float a2 = 0.f;
    #pragma unroll
    for (int f = l * 4; f < E; f += 64) {
        float4 w4 = *(const float4*)(wrow + f);
        float4 x4 = *(const float4*)(qrow + f);
        a2 += w4.x*x4.x + w4.y*x4.y + w4.z*x4.z + w4.w*x4.w;
    }
    float a3 = 0.f;
    if (b == 0) {   // bkp[e] = Wc2[e,:]·ipb[E:2E]
        const float* c2 = crow + CD;
        const float* bk = ipb + E;
        #pragma unroll
        for (int f = l * 4; f < E; f += 64) {
            float4 w4 = *(const float4*)(c2 + f);
            float4 x4 = *(const float4*)(bk + f);
            a3 += w4.x*x4.x + w4.y*x4.y + w4.z*x4.z + w4.w*x4.w;
        }
    }
    #pragma unroll
    for (int m = 8; m >= 1; m >>= 1) {
        a1 += __shfl_xor(a1, m, 64);
        a2 += __shfl_xor(a2, m, 64);
        a3 += __shfl_xor(a3, m, 64);
    }
    if (l == 0) {
        ws[OFF_CTXP + b*E + e] = a1 + cb[e];
        ws[OFF_Q0   + b*E + e] = a2 + ipb[e];
        if (b == 0) ws[OFF_BKP + e] = a3;
    }
}

// ---------------- stage 2: q1s (scaled), ck ----------------
__global__ __launch_bounds__(256) void k_pre2(
    const float* __restrict__ cw, float* __restrict__ ws)
{
    int b  = blockIdx.x >> 6;
    int et = blockIdx.x & 63;
    int grp = threadIdx.x >> 4, l = threadIdx.x & 15;
    int e = et * 16 + grp;
    const float* q0 = ws + OFF_Q0 + b*E;
    const float* c2row = cw + (size_t)e * (CD + E) + CD;  // Wc2 row e
    float acc = 0.f;
    #pragma unroll
    for (int f = l * 4; f < E; f += 64) {
        float4 w4 = *(const float4*)(c2row + f);
        float4 x4 = *(const float4*)(q0 + f);
        acc += w4.x*x4.x + w4.y*x4.y + w4.z*x4.z + w4.w*x4.w;
    }
    #pragma unroll
    for (int m = 8; m >= 1; m >>= 1) acc += __shfl_xor(acc, m, 64);
    if (l == 0) {
        float ctxp = ws[OFF_CTXP + b*E + e];
        ws[OFF_Q1S + b*E + e] = (ctxp + acc) * SCALE;
        ws[OFF_CK  + b*E + e] = ctxp + ws[OFF_BKP + e];
    }
}

// ---------------- stage 3: t_T[f][bh] ----------------
__global__ __launch_bounds__(256) void k_pre3(
    const float* __restrict__ cw, float* __restrict__ ws)
{
    int bh = blockIdx.x >> 2;
    int f  = ((blockIdx.x & 3) << 8) + threadIdx.x;
    int b = bh >> 4, h = bh & 15;
    const float* q1 = ws + OFF_Q1S + b*E + h*DH;
    float acc = 0.f;
    #pragma unroll 8
    for (int d = 0; d < DH; ++d)
        acc += q1[d] * cw[(size_t)(h*DH + d)*(CD+E) + CD + f];
    ws[OFF_TT + f*256 + bh] = acc;
}

// ---------------- stage 3b: c0[bh], score at s=S ----------------
__global__ __launch_bounds__(256) void k_pre3b(
    const float* __restrict__ bias_k, float* __restrict__ ws)
{
    int bh = threadIdx.x;        // 1 block of 256
    int b = bh >> 4, h = bh & 15;
    const float* q1 = ws + OFF_Q1S + b*E + h*DH;
    const float* ck = ws + OFF_CK  + b*E + h*DH;
    const float* bk = bias_k + h*DH;
    float c0 = 0.f, sb = 0.f;
    for (int d = 0; d < DH; ++d) { float q = q1[d]; c0 += q*ck[d]; sb += q*bk[d]; }
    ws[OFF_C0 + bh] = c0;
    ws[OFF_SC + (size_t)bh*SPAD + S] = sb;   // bias_k position score
}

// ---------------- g_part[kc][bh][e] ----------------
__global__ __launch_bounds__(256) void k_g(
    const float* __restrict__ ipw, float* __restrict__ ws)
{
    int kc = blockIdx.x >> 6;            // 0..3  (f chunk of 256)
    int nt = (blockIdx.x >> 4) & 3;      // n tile of 256
    int mt = blockIdx.x & 15;            // m tile of 16 (bh)
    int n  = (nt << 8) + threadIdx.x;
    int m0 = mt << 4;
    int f0 = kc << 8;
    const float* tT = ws + OFF_TT;
    const float* wk = ipw + (size_t)E * E;   // Wk rows
    float acc[16];
    #pragma unroll
    for (int m = 0; m < 16; ++m) acc[m] = 0.f;
    for (int f = f0; f < f0 + 256; ++f) {
        float wv = wk[(size_t)f*E + n];
        const float* tr = tT + f*256 + m0;   // uniform -> scalar loads
        #pragma unroll
        for (int m = 0; m < 16; ++m) acc[m] += tr[m] * wv;
    }
    float* gp = ws + OFF_GP + (size_t)kc * (256*E);
    #pragma unroll
    for (int m = 0; m < 16; ++m) gp[(size_t)(m0+m)*E + n] = acc[m];
}

// ---------------- sum 4 g partials into slab 0 ----------------
__global__ __launch_bounds__(256) void k_gsum(float* __restrict__ ws)
{
    int id = blockIdx.x * 256 + threadIdx.x;   // 262144 threads
    float a = ws[OFF_GP + id]
            + ws[OFF_GP + 1*(256*E) + id]
            + ws[OFF_GP + 2*(256*E) + id]
            + ws[OFF_GP + 3*(256*E) + id];
    ws[OFF_GP + id] = a;
}

// ---------------- scores[bh][s] = key·g + c0 ----------------------------
// lane = s-row (64 rows/wave), wave = e-chunk of 128. g reads are
// wave-uniform LDS broadcasts; key reads consume full 64B lines per lane.
// Cross-wave e-reduction via LDS partials (17-float stride, conflict-free).
__global__ __launch_bounds__(512) void k_scores(
    const float* __restrict__ key, float* __restrict__ ws)
{
    __shared__ float lds[16384];   // phase 1: g[h][e] (64 KB); phase 2: partials
    int b  = blockIdx.x >> 5;      // batch
    int sc = blockIdx.x & 31;      // s-chunk of 64
    const float* gsrc = ws + OFF_GP + (size_t)b * (16*1024);
    for (int i = threadIdx.x; i < 4096; i += 512)
        ((float4*)lds)[i] = ((const float4*)gsrc)[i];
    __syncthreads();

    int w = threadIdx.x >> 6, l = threadIdx.x & 63;
    int s = sc*64 + l;
    const float* kr = key + (((size_t)s*B + b) << 10) + w*128;
    float acc[16];
    #pragma unroll
    for (int h = 0; h < 16; ++h) acc[h] = 0.f;

    const float4* gb0 = (const float4*)lds + w*32;   // e-base = w*128
    for (int win = 0; win < 8; ++win) {
        const float* kp = kr + win*16;               // full 64B line per lane
        float4 k0 = *(const float4*)(kp);
        float4 k1 = *(const float4*)(kp + 4);
        float4 k2 = *(const float4*)(kp + 8);
        float4 k3 = *(const float4*)(kp + 12);
        const float4* gb = gb0 + win*4;
        #pragma unroll
        for (int h = 0; h < 16; ++h) {
            float4 g0 = gb[h*256];
            float4 g1 = gb[h*256 + 1];
            float4 g2 = gb[h*256 + 2];
            float4 g3 = gb[h*256 + 3];
            acc[h] += k0.x*g0.x + k0.y*g0.y + k0.z*g0.z + k0.w*g0.w
                    + k1.x*g1.x + k1.y*g1.y + k1.z*g1.z + k1.w*g1.w
                    + k2.x*g2.x + k2.y*g2.y + k2.z*g2.z + k2.w*g2.w
                    + k3.x*g3.x + k3.y*g3.y + k3.z*g3.z + k3.w*g3.w;
        }
    }
    __syncthreads();   // done reading g; reuse LDS for partials
    float* pr = lds + (w*64 + l)*17;     // [8][64][17] = 8704 floats
    #pragma unroll
    for (int h = 0; h < 16; ++h) pr[h] = acc[h];
    __syncthreads();

    // reduce over 8 waves: thread -> (s2 = tid&63, hh = tid>>6 -> 2 heads)
    int s2 = threadIdx.x & 63, hh = threadIdx.x >> 6;
    float r0 = 0.f, r1 = 0.f;
    #pragma unroll
    for (int ww = 0; ww < 8; ++ww) {
        const float* q = lds + (ww*64 + s2)*17 + hh*2;
        r0 += q[0]; r1 += q[1];
    }
    int bh = b*16 + hh*2;
    int ss = sc*64 + s2;
    ws[OFF_SC + (size_t)bh*SPAD + ss]     = r0 + ws[OFF_C0 + bh];
    ws[OFF_SC + (size_t)(bh+1)*SPAD + ss] = r1 + ws[OFF_C0 + bh + 1];
}

// ---------------- softmax per (b,h) row; write w_T[b][s][h] ----------------
__global__ __launch_bounds__(256) void k_softmax(float* __restrict__ ws)
{
    int bh = blockIdx.x; int b = bh >> 4, h = bh & 15;
    int tid = threadIdx.x, lane = tid & 63, wid = tid >> 6;
    const float* row = ws + OFF_SC + (size_t)bh*SPAD;
    __shared__ float red[4];
    float v[9];
    float m = -1e30f;
    #pragma unroll
    for (int i = 0; i < 9; ++i) {
        int s = tid + (i << 8);
        if (s < SRC) { v[i] = row[s]; m = fmaxf(m, v[i]); } else v[i] = -1e30f;
    }
    #pragma unroll
    for (int k = 1; k < 64; k <<= 1) m = fmaxf(m, __shfl_xor(m, k, 64));
    if (lane == 0) red[wid] = m;
    __syncthreads();
    m = fmaxf(fmaxf(red[0], red[1]), fmaxf(red[2], red[3]));
    __syncthreads();
    float sum = 0.f;
    #pragma unroll
    for (int i = 0; i < 9; ++i) {
        int s = tid + (i << 8);
        if (s < SRC) { v[i] = expf(v[i] - m); sum += v[i]; }
    }
    #pragma unroll
    for (int k = 1; k < 64; k <<= 1) sum += __shfl_xor(sum, k, 64);
    if (lane == 0) red[wid] = sum;
    __syncthreads();
    sum = red[0] + red[1] + red[2] + red[3];
    float inv = 1.0f / sum;
    float* wt = ws + OFF_WT;
    #pragma unroll
    for (int i = 0; i < 9; ++i) {
        int s = tid + (i << 8);
        if (s < SRC) wt[((size_t)(b*SRC + s) << 4) + h] = v[i] * inv;
    }
}

// ---------------- avg_weights output ----------------
__global__ __launch_bounds__(256) void k_avg(
    const float* __restrict__ ws, float* __restrict__ out)
{
    int id = blockIdx.x * 256 + threadIdx.x;
    if (id >= B * SRC) return;
    const float* p = ws + OFF_WT + (size_t)id * 16;
    float a = 0.f;
    #pragma unroll
    for (int j = 0; j < 16; j += 4) {
        float4 w4 = *(const float4*)(p + j);
        a += w4.x + w4.y + w4.z + w4.w;
    }
    out[B*E + id] = a * (1.0f / H);
}

// ---------------- u_part[sc][b][h][f] = Σ_s w·value ----------------
__global__ __launch_bounds__(256) void k_u(
    const float* __restrict__ value, float* __restrict__ ws)
{
    int b  = blockIdx.x >> 5;
    int sc = (blockIdx.x >> 1) & 15;     // 16 s-chunks of 128
    int fh = blockIdx.x & 1;             // f half
    int f  = (fh << 9) + threadIdx.x * 2;
    float2 acc[16];
    #pragma unroll
    for (int h = 0; h < 16; ++h) { acc[h].x = 0.f; acc[h].y = 0.f; }
    int s0 = sc << 7;
    for (int i = 0; i < 128; ++i) {
        int s = s0 + i;
        const float* wr = ws + OFF_WT + ((size_t)(b*SRC + s) << 4); // uniform
        float2 vv = *(const float2*)(value + (((size_t)s*B + b) << 10) + f);
        #pragma unroll
        for (int h = 0; h < 16; ++h) {
            float wv = wr[h];
            acc[h].x += wv * vv.x; acc[h].y += wv * vv.y;
        }
    }
    float* up = ws + OFF_UP + ((size_t)(sc*B + b) << 4) * E;
    #pragma unroll
    for (int h = 0; h < 16; ++h)
        *(float2*)(up + (size_t)h*E + f) = acc[h];
}

// ---------------- reduce u_part ----------------
__global__ __launch_bounds__(256) void k_ured(float* __restrict__ ws)
{
    int id = blockIdx.x * 256 + threadIdx.x;   // 262144 threads
    float a = 0.f;
    #pragma unroll
    for (int c = 0; c < 16; ++c) a += ws[OFF_UP + (size_t)c*(B*H*E) + id];
    ws[OFF_U + id] = a;
}

// ---------------- attn_pre[b][e] (16-lane-group GEMV) ----------------
__global__ __launch_bounds__(256) void k_attnpre(
    const float* __restrict__ ipw, const float* __restrict__ ipb,
    const float* __restrict__ bias_v, float* __restrict__ ws)
{
    int b  = blockIdx.x >> 6;
    int et = blockIdx.x & 63;
    int grp = threadIdx.x >> 4, l = threadIdx.x & 15;
    int e = et * 16 + grp;
    int h = e >> 6;
    const float* wvr = ipw + (size_t)(2*E + e) * E;   // Wv row e
    const float* ur  = ws + OFF_U + (size_t)(b*16 + h) * E;
    float acc = 0.f;
    #pragma unroll
    for (int ff = l * 4; ff < E; ff += 64) {
        float4 w4 = *(const float4*)(wvr + ff);
        float4 u4 = *(const float4*)(ur + ff);
        acc += w4.x*u4.x + w4.y*u4.y + w4.z*u4.z + w4.w*u4.w;
    }
    #pragma unroll
    for (int m = 8; m >= 1; m >>= 1) acc += __shfl_xor(acc, m, 64);
    if (l == 0) {
        float wS = ws[OFF_WT + ((size_t)(b*SRC + S) << 4) + h];
        ws[OFF_AP + b*E + e] = acc + ipb[2*E + e] * (1.0f - wS) + wS * bias_v[e];
    }
}

// ---------------- out projection (16-lane-group GEMV) ----------------
__global__ __launch_bounds__(256) void k_out(
    const float* __restrict__ ow, const float* __restrict__ ob,
    const float* __restrict__ ws, float* __restrict__ out)
{
    int b  = blockIdx.x >> 6;
    int et = blockIdx.x & 63;
    int grp = threadIdx.x >> 4, l = threadIdx.x & 15;
    int o = et * 16 + grp;
    const float* wr = ow + (size_t)o * E;
    const float* ap = ws + OFF_AP + b*E;
    float acc = 0.f;
    #pragma unroll
    for (int e = l * 4; e < E; e += 64) {
        float4 w4 = *(const float4*)(wr + e);
        float4 a4 = *(const float4*)(ap + e);
        acc += w4.x*a4.x + w4.y*a4.y + w4.z*a4.z + w4.w*a4.w;
    }
    #pragma unroll
    for (int m = 8; m >= 1; m >>= 1) acc += __shfl_xor(acc, m, 64);
    if (l == 0) out[b*E + o] = acc + ob[o];
}

extern "C" void kernel_launch(void* const* d_in, const int* in_sizes, int n_in,
                              void* d_out, int out_size, void* d_ws, size_t ws_size,
                              hipStream_t stream)
{
    const float* query   = (const float*)d_in[0];
    const float* key     = (const float*)d_in[1];
    const float* value   = (const float*)d_in[2];
    const float* context = (const float*)d_in[3];
    const float* ipw     = (const float*)d_in[4];
    const float* ipb     = (const float*)d_in[5];
    const float* cw      = (const float*)d_in[6];
    const float* cb      = (const float*)d_in[7];
    const float* ow      = (const float*)d_in[8];
    const float* ob      = (const float*)d_in[9];
    const float* bias_k  = (const float*)d_in[10];
    const float* bias_v  = (const float*)d_in[11];
    float* out = (float*)d_out;
    float* ws  = (float*)d_ws;

    hipLaunchKernelGGL(k_pre1,    dim3(1024), dim3(256),  0, stream, query, context, ipw, ipb, cw, cb, ws);
    hipLaunchKernelGGL(k_pre2,    dim3(1024), dim3(256),  0, stream, cw, ws);
    hipLaunchKernelGGL(k_pre3,    dim3(1024), dim3(256),  0, stream, cw, ws);
    hipLaunchKernelGGL(k_pre3b,   dim3(1),    dim3(256),  0, stream, bias_k, ws);
    hipLaunchKernelGGL(k_g,       dim3(256),  dim3(256),  0, stream, ipw, ws);
    hipLaunchKernelGGL(k_gsum,    dim3(1024), dim3(256),  0, stream, ws);
    hipLaunchKernelGGL(k_scores,  dim3(512),  dim3(512),  0, stream, key, ws);
    hipLaunchKernelGGL(k_softmax, dim3(256),  dim3(256),  0, stream, ws);
    hipLaunchKernelGGL(k_avg,     dim3(129),  dim3(256),  0, stream, ws, out);
    hipLaunchKernelGGL(k_u,       dim3(512),  dim3(256),  0, stream, value, ws);
    hipLaunchKernelGGL(k_ured,    dim3(1024), dim3(256),  0, stream, ws);
    hipLaunchKernelGGL(k_attnpre, dim3(1024), dim3(256),  0, stream, ipw, ipb, bias_v, ws);
    hipLaunchKernelGGL(k_out,     dim3(1024), dim3(256),  0, stream, ow, ob, ws, out);
}